// Round 1
// baseline (415.113 us; speedup 1.0000x reference)
//
#include <hip/hip_runtime.h>
#include <math.h>

#define N 8192
#define D 128
#define TI 32
#define TJ 64
#define SPLIT 4
#define JTILES_PER_SPLIT ((N / SPLIT) / TJ)  // 32

// ---------------------------------------------------------------------------
// Kernel 1: normalize rows, write k-major transpose xnT[d][r] and sq[r]
// One wave (64 lanes) per row; D=128 -> 2 elements per lane.
// ---------------------------------------------------------------------------
__global__ void normalize_kernel(const float* __restrict__ x,
                                 float* __restrict__ xnT,
                                 float* __restrict__ sq) {
    const int wave = threadIdx.x >> 6;
    const int lane = threadIdx.x & 63;
    const int r = blockIdx.x * 4 + wave;

    float v0 = x[(size_t)r * D + lane];
    float v1 = x[(size_t)r * D + lane + 64];
    float s = v0 * v0 + v1 * v1;
#pragma unroll
    for (int m = 1; m < 64; m <<= 1) s += __shfl_xor(s, m, 64);
    const float norm = sqrtf(s);
    const float n0 = v0 / norm;
    const float n1 = v1 / norm;
    // reference recomputes sq from the normalized rows
    float t = n0 * n0 + n1 * n1;
#pragma unroll
    for (int m = 1; m < 64; m <<= 1) t += __shfl_xor(t, m, 64);

    xnT[(size_t)lane * N + r]        = n0;
    xnT[(size_t)(lane + 64) * N + r] = n1;
    if (lane == 0) sq[r] = t;
}

// ---------------------------------------------------------------------------
// Kernel 2: tiled Gram + fused hardest-pos (argmax) / hardest-neg (argmin)
// Block: 256 threads as (ty 0..15) x (tx 0..15); thread tile 2 rows x 4 cols.
// Grid: (N/TI row tiles, SPLIT j-ranges). Each block scans its j-range and
// writes per-(split,row) partial bests.
// ---------------------------------------------------------------------------
__device__ __forceinline__ void update_best(float d2, bool same, bool self,
                                            int j, float& bpv, int& bpi,
                                            float& bnv, int& bni, int& flags) {
    const bool isPos = same && !self;
    const float vp = isPos ? d2 : 0.0f;          // masked positives -> 0
    if (vp > bpv) { bpv = vp; bpi = j; }         // strict > keeps first max
    const float vn = same ? INFINITY : d2;       // masked negatives -> +inf
    if (vn < bnv) { bnv = vn; bni = j; }         // strict < keeps first min
    flags |= (isPos ? 1 : 0) | (same ? 0 : 2);
}

__global__ __launch_bounds__(256) void miner_kernel(
    const float* __restrict__ xnT, const float* __restrict__ sq,
    const int* __restrict__ labels,
    float* __restrict__ pv, int* __restrict__ pi,
    float* __restrict__ nv, int* __restrict__ ni, int* __restrict__ fl) {
    __shared__ float As[D][TI];   // 16 KB, k-major
    __shared__ float Bs[D][TJ];   // 32 KB, k-major
    __shared__ int   lblj[TJ];
    __shared__ float sqj[TJ];

    const int t  = threadIdx.x;
    const int tx = t & 15;        // column group: cols 4*tx .. 4*tx+3
    const int ty = t >> 4;        // row pair:     rows 2*ty, 2*ty+1
    const int r0 = blockIdx.x * TI;
    const int split = blockIdx.y;
    const int jbase = split * (N / SPLIT);

    // Stage A tile (128 x 32 floats = 1024 float4; 4 per thread), coalesced.
#pragma unroll
    for (int s = 0; s < (D * TI) / (4 * 256); ++s) {
        const int m = t + s * 256;
        const int k = m >> 3;
        const int c = (m & 7) << 2;
        *(float4*)&As[k][c] = *(const float4*)(xnT + (size_t)k * N + r0 + c);
    }

    const int rA = r0 + 2 * ty;
    const int rB = rA + 1;
    const float sqiA = sq[rA], sqiB = sq[rB];
    const int   liA = labels[rA], liB = labels[rB];

    float bpvA = -1.0f, bpvB = -1.0f;
    int   bpiA = 0,     bpiB = 0;
    float bnvA = INFINITY, bnvB = INFINITY;
    int   bniA = 0,     bniB = 0;
    int   flagsA = 0,   flagsB = 0;   // bit0: pos exists, bit1: neg exists

    for (int jt = 0; jt < JTILES_PER_SPLIT; ++jt) {
        const int j0 = jbase + jt * TJ;
        __syncthreads();
        // Stage B tile (128 x 64 floats = 2048 float4; 8 per thread).
#pragma unroll
        for (int s = 0; s < (D * TJ) / (4 * 256); ++s) {
            const int m = t + s * 256;
            const int k = m >> 4;
            const int c = (m & 15) << 2;
            *(float4*)&Bs[k][c] = *(const float4*)(xnT + (size_t)k * N + j0 + c);
        }
        if (t < TJ)            lblj[t]      = labels[j0 + t];
        else if (t < 2 * TJ)   sqj[t - TJ]  = sq[j0 + t - TJ];
        __syncthreads();

        float acc00 = 0.f, acc01 = 0.f, acc02 = 0.f, acc03 = 0.f;
        float acc10 = 0.f, acc11 = 0.f, acc12 = 0.f, acc13 = 0.f;
#pragma unroll 16
        for (int k = 0; k < D; ++k) {
            const float a0 = As[k][2 * ty];
            const float a1 = As[k][2 * ty + 1];
            const float4 b = *(const float4*)&Bs[k][4 * tx];
            acc00 = fmaf(a0, b.x, acc00);
            acc01 = fmaf(a0, b.y, acc01);
            acc02 = fmaf(a0, b.z, acc02);
            acc03 = fmaf(a0, b.w, acc03);
            acc10 = fmaf(a1, b.x, acc10);
            acc11 = fmaf(a1, b.y, acc11);
            acc12 = fmaf(a1, b.z, acc12);
            acc13 = fmaf(a1, b.w, acc13);
        }

        const float aA[4] = {acc00, acc01, acc02, acc03};
        const float aB[4] = {acc10, acc11, acc12, acc13};
#pragma unroll
        for (int c = 0; c < 4; ++c) {
            const int jj = 4 * tx + c;
            const int j = j0 + jj;
            const int lj = lblj[jj];
            const float sj = sqj[jj];
            {
                const float d2 = fmaxf(sqiA + sj - 2.0f * aA[c], 0.0f);
                update_best(d2, lj == liA, j == rA, j, bpvA, bpiA, bnvA, bniA, flagsA);
            }
            {
                const float d2 = fmaxf(sqiB + sj - 2.0f * aB[c], 0.0f);
                update_best(d2, lj == liB, j == rB, j, bpvB, bpiB, bnvB, bniB, flagsB);
            }
        }
    }

    // Reduce across the 16 tx-lanes that share the same rows (xor<16 stays
    // inside a 16-lane group of the wave). Tie-break: smaller index.
#pragma unroll
    for (int m = 1; m < 16; m <<= 1) {
        {
            const float ov = __shfl_xor(bpvA, m, 64); const int oi = __shfl_xor(bpiA, m, 64);
            if (ov > bpvA || (ov == bpvA && oi < bpiA)) { bpvA = ov; bpiA = oi; }
        }
        {
            const float ov = __shfl_xor(bpvB, m, 64); const int oi = __shfl_xor(bpiB, m, 64);
            if (ov > bpvB || (ov == bpvB && oi < bpiB)) { bpvB = ov; bpiB = oi; }
        }
        {
            const float ov = __shfl_xor(bnvA, m, 64); const int oi = __shfl_xor(bniA, m, 64);
            if (ov < bnvA || (ov == bnvA && oi < bniA)) { bnvA = ov; bniA = oi; }
        }
        {
            const float ov = __shfl_xor(bnvB, m, 64); const int oi = __shfl_xor(bniB, m, 64);
            if (ov < bnvB || (ov == bnvB && oi < bniB)) { bnvB = ov; bniB = oi; }
        }
        flagsA |= __shfl_xor(flagsA, m, 64);
        flagsB |= __shfl_xor(flagsB, m, 64);
    }

    if (tx == 0) {
        const size_t base = (size_t)split * N;
        pv[base + rA] = bpvA; pi[base + rA] = bpiA;
        nv[base + rA] = bnvA; ni[base + rA] = bniA;
        fl[base + rA] = flagsA;
        pv[base + rB] = bpvB; pi[base + rB] = bpiB;
        nv[base + rB] = bnvB; ni[base + rB] = bniB;
        fl[base + rB] = flagsB;
    }
}

// ---------------------------------------------------------------------------
// Kernel 3: merge the SPLIT partials per row; write outputs (int32):
// [anchor 0..N) [pos N..2N) [neg 2N..3N) [keep 3N..4N)
// ---------------------------------------------------------------------------
__global__ void merge_kernel(const float* __restrict__ pv, const int* __restrict__ pi,
                             const float* __restrict__ nv, const int* __restrict__ ni,
                             const int* __restrict__ fl, int* __restrict__ out) {
    const int r = blockIdx.x * blockDim.x + threadIdx.x;
    float bpv = -1.0f; int bpi = 0;
    float bnv = INFINITY; int bni = 0;
    int flags = 0;
#pragma unroll
    for (int s = 0; s < SPLIT; ++s) {
        const size_t idx = (size_t)s * N + r;
        const float v = pv[idx]; const int i = pi[idx];
        if (v > bpv || (v == bpv && i < bpi)) { bpv = v; bpi = i; }
        const float w = nv[idx]; const int u = ni[idx];
        if (w < bnv || (w == bnv && u < bni)) { bnv = w; bni = u; }
        flags |= fl[idx];
    }
    out[r]         = r;
    out[N + r]     = bpi;
    out[2 * N + r] = bni;
    out[3 * N + r] = (flags == 3) ? 1 : 0;
}

extern "C" void kernel_launch(void* const* d_in, const int* in_sizes, int n_in,
                              void* d_out, int out_size, void* d_ws, size_t ws_size,
                              hipStream_t stream) {
    const float* x      = (const float*)d_in[0];
    const int*   labels = (const int*)d_in[1];
    int* out = (int*)d_out;

    float* ws  = (float*)d_ws;
    float* xnT = ws;                                  // N*D floats (4 MB)
    float* sq  = xnT + (size_t)N * D;                 // N floats
    float* pv  = sq + N;                              // SPLIT*N
    int*   pi  = (int*)(pv + (size_t)SPLIT * N);      // SPLIT*N
    float* nv  = (float*)(pi + (size_t)SPLIT * N);    // SPLIT*N
    int*   ni  = (int*)(nv + (size_t)SPLIT * N);      // SPLIT*N
    int*   fl  = ni + (size_t)SPLIT * N;              // SPLIT*N

    normalize_kernel<<<N / 4, 256, 0, stream>>>(x, xnT, sq);
    miner_kernel<<<dim3(N / TI, SPLIT), 256, 0, stream>>>(xnT, sq, labels,
                                                          pv, pi, nv, ni, fl);
    merge_kernel<<<N / 256, 256, 0, stream>>>(pv, pi, nv, ni, fl, out);
}

// Round 3
// 239.089 us; speedup vs baseline: 1.7362x; 1.7362x over previous
//
#include <hip/hip_runtime.h>
#include <math.h>

#define N 8192
#define D 128
#define NC 256                 // number of classes
#define NT 128                 // number of 64-wide tiles along each dim
#define NBLK (NT * (NT + 1) / 2)

// ---------------------------------------------------------------------------
// Kernel 1: normalize rows, write k-major transpose xnT[d][r] and sq[r]
// ---------------------------------------------------------------------------
__global__ void normalize_kernel(const float* __restrict__ x,
                                 float* __restrict__ xnT,
                                 float* __restrict__ sq) {
    const int wave = threadIdx.x >> 6;
    const int lane = threadIdx.x & 63;
    const int r = blockIdx.x * 4 + wave;

    float v0 = x[(size_t)r * D + lane];
    float v1 = x[(size_t)r * D + lane + 64];
    float s = v0 * v0 + v1 * v1;
#pragma unroll
    for (int m = 1; m < 64; m <<= 1) s += __shfl_xor(s, m, 64);
    const float norm = sqrtf(s);
    const float n0 = v0 / norm;
    const float n1 = v1 / norm;
    float t = n0 * n0 + n1 * n1;
#pragma unroll
    for (int m = 1; m < 64; m <<= 1) t += __shfl_xor(t, m, 64);

    xnT[(size_t)lane * N + r]        = n0;
    xnT[(size_t)(lane + 64) * N + r] = n1;
    if (lane == 0) sq[r] = t;
}

// ---------------------------------------------------------------------------
// Kernel 2: init packed best arrays + histogram bins
// ---------------------------------------------------------------------------
__global__ void init_kernel(unsigned long long* __restrict__ pos_pack,
                            unsigned long long* __restrict__ neg_pack,
                            int* __restrict__ hist) {
    const int t = blockIdx.x * 256 + threadIdx.x;
    if (t < N) { pos_pack[t] = 0ULL; neg_pack[t] = ~0ULL; }
    if (t < NC) hist[t] = 0;
}

// ---------------------------------------------------------------------------
// Kernel 3: label histogram (exact keep-mask computation)
// ---------------------------------------------------------------------------
__global__ void hist_kernel(const int* __restrict__ labels, int* __restrict__ hist) {
    __shared__ int h[NC];
    h[threadIdx.x] = 0;
    __syncthreads();
    const int base = blockIdx.x * 1024;
#pragma unroll
    for (int s = 0; s < 4; ++s) atomicAdd(&h[labels[base + s * 256 + threadIdx.x]], 1);
    __syncthreads();
    atomicAdd(&hist[threadIdx.x], h[threadIdx.x]);
}

// ---------------------------------------------------------------------------
// Kernel 4: symmetric tiled Gram + fused arg-reductions.
// Packed-u64 commits are UNCONDITIONAL device atomics: max/min over a
// deterministic multiset -> bit-deterministic result across replays
// (the round-2 guarded-read version lost updates via stale L2 reads).
// ---------------------------------------------------------------------------
__device__ __forceinline__ unsigned int fbits(float f) {
    union { float f; unsigned int u; } x; x.f = f; return x.u;
}
__device__ __forceinline__ unsigned long long pack_pos(float v, int j) {
    return ((unsigned long long)fbits(v) << 32) | (unsigned int)(8191 - j);
}
__device__ __forceinline__ unsigned long long pack_neg(float v, int j) {
    return ((unsigned long long)fbits(v) << 32) | (unsigned int)j;
}
__device__ __forceinline__ void red_max(float& v, int& j, int mask) {
    const float ov = __shfl_xor(v, mask, 64);
    const int   oj = __shfl_xor(j, mask, 64);
    if (ov > v || (ov == v && oj < j)) { v = ov; j = oj; }
}
__device__ __forceinline__ void red_min(float& v, int& j, int mask) {
    const float ov = __shfl_xor(v, mask, 64);
    const int   oj = __shfl_xor(j, mask, 64);
    if (ov < v || (ov == v && oj < j)) { v = ov; j = oj; }
}

__global__ __launch_bounds__(256, 4) void miner_kernel(
    const float* __restrict__ xnT, const float* __restrict__ sq,
    const int* __restrict__ labels,
    unsigned long long* __restrict__ pos_pack,
    unsigned long long* __restrict__ neg_pack) {
    __shared__ float As[64][64];   // 16 KB; reused as u64[8][64] scratch in J-merge
    __shared__ float Bs[64][64];   // 16 KB
    __shared__ float sqI[64], sqJ[64];
    __shared__ int   lbI[64], lbJ[64];

    const int t  = threadIdx.x;
    const int tx = t & 15;
    const int ty = t >> 4;

    // decode upper-triangular (bi, bj), bi <= bj
    const int b = blockIdx.x;
    int bi = (int)((257.0f - sqrtf(66049.0f - 8.0f * (float)b)) * 0.5f);
    while (bi > 0 && (bi * NT - bi * (bi - 1) / 2) > b) --bi;
    while (((bi + 1) * NT - (bi + 1) * bi / 2) <= b) ++bi;
    const int bj = bi + (b - (bi * NT - bi * (bi - 1) / 2));
    const int I0 = bi * 64, J0 = bj * 64;
    const bool diag = (bi == bj);

    if (t < 64) {
        sqI[t] = sq[I0 + t]; sqJ[t] = sq[J0 + t];
        lbI[t] = labels[I0 + t]; lbJ[t] = labels[J0 + t];
    }

    float acc[4][4] = {};
    for (int kc = 0; kc < D; kc += 64) {
        __syncthreads();
#pragma unroll
        for (int p = 0; p < 4; ++p) {
            const int lin = p * 256 + t;
            const int k = lin >> 4;
            const int c = (lin & 15) << 2;
            *(float4*)&As[k][c] = *(const float4*)(xnT + (size_t)(kc + k) * N + I0 + c);
            *(float4*)&Bs[k][c] = *(const float4*)(xnT + (size_t)(kc + k) * N + J0 + c);
        }
        __syncthreads();
#pragma unroll 8
        for (int k = 0; k < 64; ++k) {
            const float4 av = *(const float4*)&As[k][ty * 4];
            const float4 bv = *(const float4*)&Bs[k][tx * 4];
            const float a[4] = {av.x, av.y, av.z, av.w};
            const float bb[4] = {bv.x, bv.y, bv.z, bv.w};
#pragma unroll
            for (int ri = 0; ri < 4; ++ri)
#pragma unroll
                for (int ci = 0; ci < 4; ++ci)
                    acc[ri][ci] = fmaf(a[ri], bb[ci], acc[ri][ci]);
        }
    }

    // ---- epilogue ----
    int rows[4], cols[4], li[4], lj[4];
    float siv[4], sjv[4];
#pragma unroll
    for (int ri = 0; ri < 4; ++ri) {
        rows[ri] = I0 + 4 * ty + ri;
        li[ri] = lbI[4 * ty + ri];
        siv[ri] = sqI[4 * ty + ri];
    }
#pragma unroll
    for (int ci = 0; ci < 4; ++ci) {
        cols[ci] = J0 + 4 * tx + ci;
        lj[ci] = lbJ[4 * tx + ci];
        sjv[ci] = sqJ[4 * tx + ci];
    }
    float d2[4][4];
#pragma unroll
    for (int ri = 0; ri < 4; ++ri)
#pragma unroll
        for (int ci = 0; ci < 4; ++ci)
            d2[ri][ci] = fmaxf(siv[ri] + sjv[ci] - 2.0f * acc[ri][ci], 0.0f);

    // I-side: best over my 4 cols per row, reduce across tx (in-wave), commit.
    {
        float bpv[4], bnv[4]; int bpj[4], bnj[4];
#pragma unroll
        for (int ri = 0; ri < 4; ++ri) {
            bpv[ri] = -1.0f; bpj[ri] = 0; bnv[ri] = INFINITY; bnj[ri] = 0;
#pragma unroll
            for (int ci = 0; ci < 4; ++ci) {
                const bool same = (li[ri] == lj[ci]);
                const bool self = (rows[ri] == cols[ci]);
                const float vp = (same && !self) ? d2[ri][ci] : 0.0f;
                if (vp > bpv[ri]) { bpv[ri] = vp; bpj[ri] = cols[ci]; }
                const float vn = same ? INFINITY : d2[ri][ci];
                if (vn < bnv[ri]) { bnv[ri] = vn; bnj[ri] = cols[ci]; }
            }
        }
#pragma unroll
        for (int m = 1; m < 16; m <<= 1)
#pragma unroll
            for (int ri = 0; ri < 4; ++ri) {
                red_max(bpv[ri], bpj[ri], m);
                red_min(bnv[ri], bnj[ri], m);
            }
        if (tx == 0) {
#pragma unroll
            for (int ri = 0; ri < 4; ++ri) {
                atomicMax(&pos_pack[rows[ri]], pack_pos(bpv[ri], bpj[ri]));
                atomicMin(&neg_pack[rows[ri]], pack_neg(bnv[ri], bnj[ri]));
            }
        }
    }

    // J-side (transposed), skipped for diagonal blocks. In-wave reduce across
    // ty (masks 16/32), then cross-wave merge via LDS, one commit per col.
    if (!diag) {
        float bpv[4], bnv[4]; int bpj[4], bnj[4];
#pragma unroll
        for (int ci = 0; ci < 4; ++ci) {
            bpv[ci] = -1.0f; bpj[ci] = 0; bnv[ci] = INFINITY; bnj[ci] = 0;
#pragma unroll
            for (int ri = 0; ri < 4; ++ri) {
                const bool same = (li[ri] == lj[ci]);   // no self off-diagonal
                const float vp = same ? d2[ri][ci] : 0.0f;
                if (vp > bpv[ci]) { bpv[ci] = vp; bpj[ci] = rows[ri]; }
                const float vn = same ? INFINITY : d2[ri][ci];
                if (vn < bnv[ci]) { bnv[ci] = vn; bnj[ci] = rows[ri]; }
            }
        }
#pragma unroll
        for (int m = 16; m < 64; m <<= 1)
#pragma unroll
            for (int ci = 0; ci < 4; ++ci) {
                red_max(bpv[ci], bpj[ci], m);
                red_min(bnv[ci], bnj[ci], m);
            }
        // cross-wave merge via LDS scratch (reuse As: 8*64 u64 = 4 KB)
        unsigned long long* scr = (unsigned long long*)&As[0][0];
        __syncthreads();                       // As no longer read by k-loop
        const int wv = t >> 6;
        if ((t & 48) == 0) {                   // lanes 0-15 of each wave
            const int l16 = t & 15;
#pragma unroll
            for (int ci = 0; ci < 4; ++ci) {
                scr[(size_t)wv * 64 + 4 * l16 + ci]       = pack_pos(bpv[ci], bpj[ci]);
                scr[(size_t)(4 + wv) * 64 + 4 * l16 + ci] = pack_neg(bnv[ci], bnj[ci]);
            }
        }
        __syncthreads();
        if (t < 64) {
            unsigned long long mp = 0ULL, mn = ~0ULL;
#pragma unroll
            for (int w = 0; w < 4; ++w) {
                const unsigned long long p = scr[(size_t)w * 64 + t];
                const unsigned long long q = scr[(size_t)(4 + w) * 64 + t];
                if (p > mp) mp = p;
                if (q < mn) mn = q;
            }
            atomicMax(&pos_pack[J0 + t], mp);
            atomicMin(&neg_pack[J0 + t], mn);
        }
    }
}

// ---------------------------------------------------------------------------
// Kernel 5: finalize -> int32 outputs [anchor | pos | neg | keep]
// ---------------------------------------------------------------------------
__global__ void finalize_kernel(const unsigned long long* __restrict__ pos_pack,
                                const unsigned long long* __restrict__ neg_pack,
                                const int* __restrict__ labels,
                                const int* __restrict__ hist,
                                int* __restrict__ out) {
    const int r = blockIdx.x * 256 + threadIdx.x;
    out[r]         = r;
    out[N + r]     = 8191 - (int)(pos_pack[r] & 0xFFFFFFFFULL);
    out[2 * N + r] = (int)(neg_pack[r] & 0xFFFFFFFFULL);
    const int cnt = hist[labels[r]];
    out[3 * N + r] = (cnt >= 2 && cnt < N) ? 1 : 0;
}

extern "C" void kernel_launch(void* const* d_in, const int* in_sizes, int n_in,
                              void* d_out, int out_size, void* d_ws, size_t ws_size,
                              hipStream_t stream) {
    const float* x      = (const float*)d_in[0];
    const int*   labels = (const int*)d_in[1];
    int* out = (int*)d_out;

    float* ws  = (float*)d_ws;
    float* xnT = ws;                                        // N*D floats (4 MB)
    float* sq  = xnT + (size_t)N * D;                       // N floats
    unsigned long long* pos_pack =
        (unsigned long long*)(sq + N);                      // N u64
    unsigned long long* neg_pack = pos_pack + N;            // N u64
    int* hist = (int*)(neg_pack + N);                       // NC ints

    init_kernel<<<N / 256, 256, 0, stream>>>(pos_pack, neg_pack, hist);
    normalize_kernel<<<N / 4, 256, 0, stream>>>(x, xnT, sq);
    hist_kernel<<<N / 1024, 256, 0, stream>>>(labels, hist);
    miner_kernel<<<NBLK, 256, 0, stream>>>(xnT, sq, labels, pos_pack, neg_pack);
    finalize_kernel<<<N / 256, 256, 0, stream>>>(pos_pack, neg_pack, labels, hist, out);
}